// Round 9
// baseline (603.170 us; speedup 1.0000x reference)
//
#include <hip/hip_runtime.h>
#include <stdint.h>

// E=8 experts, C=1024, H=2048, I=4096.
//   gate_up = X @ Wgu ; act = silu(gate)*up ; out = act @ Wd
// Round 9: BK=64 4-phase schedule with ONE barrier per K-tile.
// Hazard analysis: reads during tile t touch only buf(t&1); stages during
// tile t touch only buf((t+1)&1) -> the only sync needed is a per-tile
// {vmcnt(0); s_barrier} at the tile boundary. Round-8's per-phase barriers
// were overhead, and its vmcnt(2) at phase 3 was a latent race (A pieces 1,3
// still in flight but read at next phase 0). All stage-issues occur >=1
// phase before the drain, so vmcnt(0) is latency-covered (L2 ~200-300cy).
// Per-phase lgkmcnt(0)+sched_barrier(0) kept (rule 18). setprio around MFMA.
// Swizzle kb^=(row&7)<<4 (2-way banks free, row-window coalescing kept).
// silu fused in gemm1 epilogue via gate|up B-row permutation.

#define E_  8
#define C_  1024
#define H_  2048
#define I_  4096
#define N1_ 8192   // 2*I

typedef __bf16 bf16x8 __attribute__((ext_vector_type(8)));
typedef float  f32x4  __attribute__((ext_vector_type(4)));

typedef __attribute__((address_space(3))) unsigned       lds_uint;
typedef const __attribute__((address_space(1))) unsigned glob_uint;

__device__ __forceinline__ void gload_lds16(const void* g, void* l) {
    __builtin_amdgcn_global_load_lds((glob_uint*)g, (lds_uint*)l, 16, 0, 0);
}

__device__ __forceinline__ unsigned short f2bf(float f) {
    union { float f; unsigned u; } v; v.f = f;
    unsigned u = v.u;
    return (unsigned short)((u + 0x7FFFu + ((u >> 16) & 1u)) >> 16);  // RNE
}

// ---------------- elementwise fp32 -> bf16 (X only) ----------------
__global__ void k_convert(const float* __restrict__ src,
                          unsigned short* __restrict__ dst, int n8) {
    int idx = blockIdx.x * blockDim.x + threadIdx.x;
    int stride = gridDim.x * blockDim.x;
    for (int i = idx; i < n8; i += stride) {
        const float4* s = reinterpret_cast<const float4*>(src + (size_t)i * 8);
        float4 a = s[0], b = s[1];
        ushort4 lo, hi;
        lo.x = f2bf(a.x); lo.y = f2bf(a.y); lo.z = f2bf(a.z); lo.w = f2bf(a.w);
        hi.x = f2bf(b.x); hi.y = f2bf(b.y); hi.z = f2bf(b.z); hi.w = f2bf(b.w);
        ushort4* d = reinterpret_cast<ushort4*>(dst + (size_t)i * 8);
        d[0] = lo; d[1] = hi;
    }
}

// ---------------- tiled transpose + convert: [R][Cc] f32 -> [Cc][R] bf16 ----
__global__ void k_transpose(const float* __restrict__ src,
                            unsigned short* __restrict__ dst, int R, int Cc) {
    __shared__ unsigned short tile[64][68];
    const int e = blockIdx.z;
    const float* s = src + (size_t)e * R * Cc;
    unsigned short* d = dst + (size_t)e * R * Cc;
    const int r0 = blockIdx.y * 64;
    const int c0 = blockIdx.x * 64;
    const int t = threadIdx.x;
    {
        int row = t >> 4;           // 0..15
        int col = (t & 15) * 4;     // 0..60
        #pragma unroll
        for (int i = 0; i < 4; ++i) {
            int rr = row + i * 16;
            float4 v = *reinterpret_cast<const float4*>(s + (size_t)(r0 + rr) * Cc + c0 + col);
            ushort4 b;
            b.x = f2bf(v.x); b.y = f2bf(v.y); b.z = f2bf(v.z); b.w = f2bf(v.w);
            *reinterpret_cast<ushort4*>(&tile[rr][col]) = b;
        }
    }
    __syncthreads();
    {
        const int l = t & 15;
        const int g = t >> 4;
        #pragma unroll
        for (int p = 0; p < 4; ++p) {
            int oc = p * 16 + g;
            ushort4 b;
            b.x = tile[4 * l + 0][oc];
            b.y = tile[4 * l + 1][oc];
            b.z = tile[4 * l + 2][oc];
            b.w = tile[4 * l + 3][oc];
            *reinterpret_cast<ushort4*>(d + (size_t)(c0 + oc) * R + r0 + 4 * l) = b;
        }
    }
}

// ---------------- BK=64 staging & fragment access ----------------
// Tile region: [256 rows][128B], physical byte p: row=p>>7, off=p&127,
// logical kb = off ^ ((row&7)<<4)  (involution; 2-way banks; within-row
// permutation keeps gload coalescing). Piece j = rows 64j..64j+63 (8 KiB).
template<int LD, bool PERM>
__device__ __forceinline__ void stageOp(const char* __restrict__ gbase,
                                        char* region, int j, int tid, int wave) {
    unsigned p   = (unsigned)(j * 8192 + tid * 16);
    unsigned row = p >> 7;
    unsigned kb  = (p & 127u) ^ ((row & 7u) << 4);
    size_t grow;
    if constexpr (PERM)
        grow = (size_t)((row >> 6) * 32 + ((row >> 4) & 1u) * 16 + (row & 15u))
             + (size_t)((row >> 5) & 1u) * I_;
    else
        grow = row;
    const char* gp = gbase + grow * (size_t)LD + kb;
    void* lp = region + j * 8192 + wave * 1024;   // wave-uniform base
    gload_lds16(gp, lp);
}

__device__ __forceinline__ const bf16x8* frag128(const char* tile, int row, int kb) {
    unsigned phys = (unsigned)(row * 128)
                  + ((unsigned)kb ^ (((unsigned)row & 7u) << 4));
    return reinterpret_cast<const bf16x8*>(tile + phys);
}

#define SBAR0 __builtin_amdgcn_sched_barrier(0)
#define MFMA_ __builtin_amdgcn_mfma_f32_16x16x32_bf16

// MODE 0: gemm1 (B=WguT with gate|up row-perm, silu epilogue -> bf16 act)
// MODE 1: gemm2 (plain, f32 out)
template<int LD, int NT, int BMG, int BNG, int MODE>
__global__ __launch_bounds__(512, 2) void k_gemm(
    const unsigned short* __restrict__ A,
    const unsigned short* __restrict__ B,
    void* __restrict__ Cout,
    size_t sA, size_t sB) {
    __shared__ char lds[2 * 65536];   // buf: A 32K | B 32K

    const int tid = threadIdx.x, lane = tid & 63, wave = tid >> 6;
    const int wm = wave >> 2, wn = wave & 3;
    const int kg = lane >> 4, r = lane & 15;

    // flattened grid, bijective XCD chunking (gridDim.x % 8 == 0), bm innermost
    unsigned flat = blockIdx.x;
    unsigned cpx = gridDim.x >> 3;
    unsigned nid = (flat & 7u) * cpx + (flat >> 3);
    const int bm = nid % BMG;
    const int bn = (nid / BMG) % BNG;
    const int e  = nid / (BMG * BNG);

    const char* gA = (const char*)(A + sA * e) + (size_t)(bm * 256) * LD;
    const char* gB = (const char*)(B + sB * e)
                   + (size_t)(bn * (MODE == 0 ? 128 : 256)) * LD;
    constexpr bool PB = (MODE == 0);

    // prologue: stage tile 0; drain; barrier
    stageOp<LD, false>(gA, lds, 0, tid, wave);
    stageOp<LD, false>(gA, lds, 1, tid, wave);
    stageOp<LD, false>(gA, lds, 2, tid, wave);
    stageOp<LD, false>(gA, lds, 3, tid, wave);
    stageOp<LD, PB>(gB, lds + 32768, 0, tid, wave);
    stageOp<LD, PB>(gB, lds + 32768, 1, tid, wave);
    stageOp<LD, PB>(gB, lds + 32768, 2, tid, wave);
    stageOp<LD, PB>(gB, lds + 32768, 3, tid, wave);
    SBAR0;
    asm volatile("s_waitcnt vmcnt(0)" ::: "memory");
    SBAR0;
    __builtin_amdgcn_s_barrier();
    SBAR0;

    f32x4 acc[8][4] = {};

    for (int t = 0; t < NT; ++t) {
        const char* Ab = lds + (t & 1) * 65536;
        const char* Bb = Ab + 32768;
        char* sAr = lds + ((t + 1) & 1) * 65536;
        char* sBr = sAr + 32768;
        const char* gAn = gA + (size_t)(t + 1) * 128;
        const char* gBn = gB + (size_t)(t + 1) * 128;
        const bool hs = (t + 1) < NT;

        bf16x8 af[8][2], b0[2][2], bg[2][2];

        // ---- phase 0: quadrant (m0-3, n0-1); stage A0-3 ----
        #pragma unroll
        for (int i = 0; i < 4; ++i)
            #pragma unroll
            for (int kk = 0; kk < 2; ++kk)
                af[i][kk] = *frag128(Ab, wm * 128 + i * 16 + r, kk * 64 + kg * 16);
        #pragma unroll
        for (int j = 0; j < 2; ++j)
            #pragma unroll
            for (int kk = 0; kk < 2; ++kk)
                b0[j][kk] = *frag128(Bb, wn * 64 + j * 16 + r, kk * 64 + kg * 16);
        if (hs) { stageOp<LD, false>(gAn, sAr, 0, tid, wave);
                  stageOp<LD, false>(gAn, sAr, 1, tid, wave);
                  stageOp<LD, false>(gAn, sAr, 2, tid, wave);
                  stageOp<LD, false>(gAn, sAr, 3, tid, wave); }
        asm volatile("s_waitcnt lgkmcnt(0)" ::: "memory");
        SBAR0;
        __builtin_amdgcn_s_setprio(1);
        #pragma unroll
        for (int mf = 0; mf < 4; ++mf)
            #pragma unroll
            for (int nf = 0; nf < 2; ++nf) {
                acc[mf][nf] = MFMA_(af[mf][0], b0[nf][0], acc[mf][nf], 0, 0, 0);
                acc[mf][nf] = MFMA_(af[mf][1], b0[nf][1], acc[mf][nf], 0, 0, 0);
            }
        __builtin_amdgcn_s_setprio(0);

        // ---- phase 1: quadrant (m4-7, n0-1); stage B0-1 ----
        #pragma unroll
        for (int i = 4; i < 8; ++i)
            #pragma unroll
            for (int kk = 0; kk < 2; ++kk)
                af[i][kk] = *frag128(Ab, wm * 128 + i * 16 + r, kk * 64 + kg * 16);
        if (hs) { stageOp<LD, PB>(gBn, sBr, 0, tid, wave);
                  stageOp<LD, PB>(gBn, sBr, 1, tid, wave); }
        asm volatile("s_waitcnt lgkmcnt(0)" ::: "memory");
        SBAR0;
        __builtin_amdgcn_s_setprio(1);
        #pragma unroll
        for (int mf = 4; mf < 8; ++mf)
            #pragma unroll
            for (int nf = 0; nf < 2; ++nf) {
                acc[mf][nf] = MFMA_(af[mf][0], b0[nf][0], acc[mf][nf], 0, 0, 0);
                acc[mf][nf] = MFMA_(af[mf][1], b0[nf][1], acc[mf][nf], 0, 0, 0);
            }
        __builtin_amdgcn_s_setprio(0);

        // ---- phase 2: quadrant (m4-7, n2-3); stage B2-3 ----
        #pragma unroll
        for (int j = 0; j < 2; ++j)
            #pragma unroll
            for (int kk = 0; kk < 2; ++kk)
                bg[j][kk] = *frag128(Bb, wn * 64 + 32 + j * 16 + r, kk * 64 + kg * 16);
        if (hs) { stageOp<LD, PB>(gBn, sBr, 2, tid, wave);
                  stageOp<LD, PB>(gBn, sBr, 3, tid, wave); }
        asm volatile("s_waitcnt lgkmcnt(0)" ::: "memory");
        SBAR0;
        __builtin_amdgcn_s_setprio(1);
        #pragma unroll
        for (int mf = 4; mf < 8; ++mf)
            #pragma unroll
            for (int nf = 0; nf < 2; ++nf) {
                acc[mf][nf + 2] = MFMA_(af[mf][0], bg[nf][0], acc[mf][nf + 2], 0, 0, 0);
                acc[mf][nf + 2] = MFMA_(af[mf][1], bg[nf][1], acc[mf][nf + 2], 0, 0, 0);
            }
        __builtin_amdgcn_s_setprio(0);

        // ---- phase 3: quadrant (m0-3, n2-3); no LDS ops ----
        __builtin_amdgcn_s_setprio(1);
        #pragma unroll
        for (int mf = 0; mf < 4; ++mf)
            #pragma unroll
            for (int nf = 0; nf < 2; ++nf) {
                acc[mf][nf + 2] = MFMA_(af[mf][0], bg[nf][0], acc[mf][nf + 2], 0, 0, 0);
                acc[mf][nf + 2] = MFMA_(af[mf][1], bg[nf][1], acc[mf][nf + 2], 0, 0, 0);
            }
        __builtin_amdgcn_s_setprio(0);

        // ---- single per-tile sync: drain stages, barrier ----
        if (hs) {
            SBAR0;
            asm volatile("s_waitcnt vmcnt(0)" ::: "memory");
            SBAR0;
            __builtin_amdgcn_s_barrier();
            SBAR0;
        }
    }

    // ---------------- epilogue ----------------
    const int row0 = bm * 256 + wm * 128 + kg * 4;   // + mf*16 + j
    if constexpr (MODE == 0) {
        // acc[mf][nf] (nf<2) = gate col bn*128+wn*32+nf*16+r; acc[mf][nf+2] = up.
        unsigned short* act = (unsigned short*)Cout + (size_t)e * C_ * I_;
        const int col0 = bn * 128 + wn * 32 + r;
        #pragma unroll
        for (int m = 0; m < 8; ++m)
            #pragma unroll
            for (int n = 0; n < 2; ++n)
                #pragma unroll
                for (int j = 0; j < 4; ++j) {
                    float g = acc[m][n][j], u = acc[m][n + 2][j];
                    float s = g / (1.0f + __expf(-g)) * u;
                    act[(size_t)(row0 + m * 16 + j) * I_ + col0 + n * 16] = f2bf(s);
                }
    } else {
        float* o = (float*)Cout + (size_t)e * C_ * H_;
        const int col0 = bn * 256 + wn * 64 + r;
        #pragma unroll
        for (int m = 0; m < 8; ++m)
            #pragma unroll
            for (int n = 0; n < 4; ++n)
                #pragma unroll
                for (int j = 0; j < 4; ++j)
                    o[(size_t)(row0 + m * 16 + j) * H_ + col0 + n * 16] = acc[m][n][j];
    }
}

// ---------------- launch ----------------
extern "C" void kernel_launch(void* const* d_in, const int* in_sizes, int n_in,
                              void* d_out, int out_size, void* d_ws, size_t ws_size,
                              hipStream_t stream) {
    const float* hs  = (const float*)d_in[0];   // [E][C][H]
    const float* wgu = (const float*)d_in[1];   // [E][H][2I]
    const float* wd  = (const float*)d_in[2];   // [E][I][H]
    float* out = (float*)d_out;

    char* ws = (char*)d_ws;
    unsigned short* Xbf  = (unsigned short*)(ws);                 //  33,554,432 B
    unsigned short* WguT = (unsigned short*)(ws +  33554432ull);  // 268,435,456 B
    unsigned short* WdT  = (unsigned short*)(ws + 301989888ull);  // 134,217,728 B
    unsigned short* actb = (unsigned short*)(ws + 436207616ull);  //  67,108,864 B
    // total: 503,316,480 bytes

    k_convert<<<2048, 256, 0, stream>>>(hs, Xbf, E_ * C_ * H_ / 8);

    dim3 tg1(N1_ / 64, H_ / 64, E_);   // Wgu [H][2I] -> WguT [2I][H]
    k_transpose<<<tg1, 256, 0, stream>>>(wgu, WguT, H_, N1_);

    // GEMM1 (fused silu): X[EC][H] x WguT(perm) -> act bf16 [EC][I]
    // BM=256 (BMG=4), 128 act cols/block (BNG=32), NT=32 (BK=64). 1024 blocks.
    k_gemm<H_ * 2, H_ / 64, 4, 32, 0><<<dim3(1024), 512, 0, stream>>>(
        Xbf, WguT, actb, (size_t)C_ * H_, (size_t)N1_ * H_);

    dim3 tg2(H_ / 64, I_ / 64, E_);    // Wd [I][H] -> WdT [H][I]
    k_transpose<<<tg2, 256, 0, stream>>>(wd, WdT, I_, H_);

    // GEMM2: act[EC][I] x WdT[H][I] -> out f32 [EC][H]
    // BM=256 (BMG=4), BN=256 (BNG=8), NT=64. 256 blocks.
    k_gemm<I_ * 2, I_ / 64, 4, 8, 1><<<dim3(256), 512, 0, stream>>>(
        actb, WdT, out, (size_t)C_ * I_, (size_t)H_ * I_);
}

// Round 10
// 479.380 us; speedup vs baseline: 1.2582x; 1.2582x over previous
//
#include <hip/hip_runtime.h>
#include <stdint.h>

// E=8 experts, C=1024, H=2048, I=4096.
//   gate_up = X @ Wgu ; act = silu(gate)*up ; out = act @ Wd
// Round 10: weight transposes ELIMINATED — B is transposed+converted inside
// the GEMM. Weights cross HBM exactly once (805 MB total vs ~1.5 GB before).
//  - A: bf16 via gload_lds, [256 rows][128B] LDS, swizzle kb^=(row&7)<<4.
//  - B: native f32 [K][N]. Per thread per K-tile: 8 k-strided dwordx4
//    (lane-coalesced 64B segments), v_cvt_pk_bf16_f32, 4 ds_write_b128
//    k-contiguous into the same swizzled layout the frag reads use.
//  - Pipeline: bk regs hold tile tau's B, loaded at p2 of tau-2, cvt+written
//    at p2 of tau-1 (~4 phases HBM cover), consumed tile tau.
//  - Counted boundary wait vmcnt(8): newest 8 outstanding = B(t+2) prefetch
//    (never drained); forces A-gloads(t+1) + B(t+1) complete. Issue order
//    pinned with sched_barrier(0).
//  - 4 phases/tile (kk x n-half quadrants), af[8] held per kk (32 VGPR).
//  - silu fused in gemm1 epilogue via gate|up column interleave (16-col
//    blocks) in the B-staging column map.

#define E_  8
#define C_  1024
#define H_  2048
#define I_  4096
#define N1_ 8192   // 2*I

typedef __bf16 bf16x8 __attribute__((ext_vector_type(8)));
typedef float  f32x4  __attribute__((ext_vector_type(4)));

typedef __attribute__((address_space(3))) unsigned       lds_uint;
typedef const __attribute__((address_space(1))) unsigned glob_uint;

__device__ __forceinline__ void gload_lds16(const void* g, void* l) {
    __builtin_amdgcn_global_load_lds((glob_uint*)g, (lds_uint*)l, 16, 0, 0);
}

__device__ __forceinline__ unsigned short f2bf(float f) {
    union { float f; unsigned u; } v; v.f = f;
    unsigned u = v.u;
    return (unsigned short)((u + 0x7FFFu + ((u >> 16) & 1u)) >> 16);  // RNE
}

#define SBAR0 __builtin_amdgcn_sched_barrier(0)
#define MFMA_ __builtin_amdgcn_mfma_f32_16x16x32_bf16

// ---------------- elementwise fp32 -> bf16 (X only) ----------------
__global__ void k_convert(const float* __restrict__ src,
                          unsigned short* __restrict__ dst, int n8) {
    int idx = blockIdx.x * blockDim.x + threadIdx.x;
    int stride = gridDim.x * blockDim.x;
    for (int i = idx; i < n8; i += stride) {
        const float4* s = reinterpret_cast<const float4*>(src + (size_t)i * 8);
        float4 a = s[0], b = s[1];
        ushort4 lo, hi;
        lo.x = f2bf(a.x); lo.y = f2bf(a.y); lo.z = f2bf(a.z); lo.w = f2bf(a.w);
        hi.x = f2bf(b.x); hi.y = f2bf(b.y); hi.z = f2bf(b.z); hi.w = f2bf(b.w);
        ushort4* d = reinterpret_cast<ushort4*>(dst + (size_t)i * 8);
        d[0] = lo; d[1] = hi;
    }
}

// ---------------- staging helpers ----------------
// A piece j (8 KiB, rows 64j..64j+63 of [256 rows][128B] swizzled tile)
template<int LD>
__device__ __forceinline__ void stageA(const char* __restrict__ gtile,
                                       char* ldst, int j, int tid, int wave) {
    unsigned p   = (unsigned)(j * 8192 + tid * 16);
    unsigned row = p >> 7;
    unsigned kb  = (p & 127u) ^ ((row & 7u) << 4);
    const char* gp = gtile + (size_t)row * LD + kb;
    void* lp = ldst + j * 8192 + wave * 1024;   // wave-uniform base
    gload_lds16(gp, lp);
}

__device__ __forceinline__ const bf16x8* frag128(const char* tile, int row, int kb) {
    unsigned phys = (unsigned)(row * 128)
                  + ((unsigned)kb ^ (((unsigned)row & 7u) << 4));
    return reinterpret_cast<const bf16x8*>(tile + phys);
}

// B: 8 k-strided dwordx4 (4 consecutive cols x 8 k-rows); kg8 pre-folded.
template<int LDB>
__device__ __forceinline__ void loadB8(const char* __restrict__ gcol, int kt,
                                       float4 (&bk)[8]) {
    const char* p = gcol + (size_t)(kt * 64) * LDB;
    #pragma unroll
    for (int i = 0; i < 8; ++i)
        bk[i] = *reinterpret_cast<const float4*>(p + (size_t)i * LDB);
}

// cvt 32 f32 -> bf16, write 4x ds_write_b128 (rows rg*4+j, kbyte kg8*16).
__device__ __forceinline__ void cvtWriteB(char* bB, const float4 (&bk)[8],
                                          int rg, int kg8) {
    const float* f = reinterpret_cast<const float*>(&bk[0]);
    #pragma unroll
    for (int j = 0; j < 4; ++j) {
        unsigned u[4];
        #pragma unroll
        for (int p2 = 0; p2 < 4; ++p2) {
            float lo = f[(2 * p2) * 4 + j];
            float hi = f[(2 * p2 + 1) * 4 + j];
            asm("v_cvt_pk_bf16_f32 %0, %1, %2" : "=v"(u[p2]) : "v"(lo), "v"(hi));
        }
        unsigned q = (unsigned)(rg * 4 + j);
        unsigned phys = q * 128 + (((unsigned)kg8 * 16) ^ ((q & 7u) << 4));
        *reinterpret_cast<uint4*>(bB + phys) = make_uint4(u[0], u[1], u[2], u[3]);
    }
}

// MODE 0: gemm1 (B=Wgu native [H][2I], gate|up 16-col interleave, silu -> bf16)
// MODE 1: gemm2 (B=Wd native [I][H], f32 out)
template<int LDA, int LDB, int NT, int BMG, int BNG, int MODE>
__global__ __launch_bounds__(512, 2) void k_gemm_f(
    const unsigned short* __restrict__ A,
    const float* __restrict__ B,
    void* __restrict__ Cout,
    size_t sA, size_t sB) {
    __shared__ char lds[131072];   // 2 bufs x (A 32K | B 32K)

    const int tid = threadIdx.x, lane = tid & 63, wave = tid >> 6;
    const int wm = wave >> 2, wn = wave & 3;
    const int kg = lane >> 4, r = lane & 15;
    const int rg = tid & 63, kg8 = tid >> 6;   // B-staging role

    // flattened grid, bijective XCD chunking (gridDim.x % 8 == 0), bm innermost
    unsigned flat = blockIdx.x;
    unsigned cpx = gridDim.x >> 3;
    unsigned nid = (flat & 7u) * cpx + (flat >> 3);
    const int bm = nid % BMG;
    const int bn = (nid / BMG) % BNG;
    const int e  = nid / (BMG * BNG);

    const char* gA = (const char*)(A + sA * e) + (size_t)(bm * 256) * LDA;
    size_t colstart;
    if constexpr (MODE == 0)
        colstart = (size_t)(bn * 128 + ((rg >> 4) & 3) * 32 + ((rg >> 2) & 1) * 16
                            + (rg & 3) * 4)
                 + (((rg >> 3) & 1) ? (size_t)I_ : (size_t)0);
    else
        colstart = (size_t)(bn * 256 + rg * 4);
    const char* gBcol = (const char*)(B + sB * e) + colstart * 4
                      + (size_t)kg8 * 8 * LDB;

    float4 bk[8];

    // ---------------- prologue ----------------
    loadB8<LDB>(gBcol, 0, bk);
    SBAR0;
    asm volatile("s_waitcnt vmcnt(0)" ::: "memory");
    SBAR0;
    cvtWriteB(lds + 32768, bk, rg, kg8);
    SBAR0;
    stageA<LDA>(gA, lds, 0, tid, wave);
    stageA<LDA>(gA, lds, 1, tid, wave);
    stageA<LDA>(gA, lds, 2, tid, wave);
    stageA<LDA>(gA, lds, 3, tid, wave);
    SBAR0;
    loadB8<LDB>(gBcol, 1, bk);
    SBAR0;
    asm volatile("s_waitcnt vmcnt(8)" ::: "memory");   // A(0) done; B(1) in flight
    asm volatile("s_waitcnt lgkmcnt(0)" ::: "memory");
    SBAR0;
    __builtin_amdgcn_s_barrier();
    SBAR0;

    f32x4 acc[8][4] = {};

    for (int t = 0; t < NT; ++t) {
        const char* Ab = lds + (t & 1) * 65536;
        const char* Bb = Ab + 32768;
        char* nA = lds + ((t + 1) & 1) * 65536;
        char* nB = nA + 32768;
        const char* gAn = gA + (size_t)(t + 1) * 128;
        const bool hs1 = (t + 1) < NT, hs2 = (t + 2) < NT;

        bf16x8 af[8], b0[2], bg[2];

        // ---- phase 0: kk0, n0-1 ----
        #pragma unroll
        for (int m = 0; m < 8; ++m)
            af[m] = *frag128(Ab, wm * 128 + m * 16 + r, kg * 16);
        #pragma unroll
        for (int n = 0; n < 2; ++n)
            b0[n] = *frag128(Bb, wn * 64 + n * 16 + r, kg * 16);
        asm volatile("s_waitcnt lgkmcnt(0)" ::: "memory");
        SBAR0;
        __builtin_amdgcn_s_setprio(1);
        #pragma unroll
        for (int m = 0; m < 8; ++m) {
            acc[m][0] = MFMA_(af[m], b0[0], acc[m][0], 0, 0, 0);
            acc[m][1] = MFMA_(af[m], b0[1], acc[m][1], 0, 0, 0);
        }
        __builtin_amdgcn_s_setprio(0);
        SBAR0;

        // ---- phase 1: kk0, n2-3; issue A01(t+1) ----
        #pragma unroll
        for (int n = 0; n < 2; ++n)
            bg[n] = *frag128(Bb, wn * 64 + 32 + n * 16 + r, kg * 16);
        if (hs1) { stageA<LDA>(gAn, nA, 0, tid, wave);
                   stageA<LDA>(gAn, nA, 1, tid, wave); }
        SBAR0;
        asm volatile("s_waitcnt lgkmcnt(0)" ::: "memory");
        SBAR0;
        __builtin_amdgcn_s_setprio(1);
        #pragma unroll
        for (int m = 0; m < 8; ++m) {
            acc[m][2] = MFMA_(af[m], bg[0], acc[m][2], 0, 0, 0);
            acc[m][3] = MFMA_(af[m], bg[1], acc[m][3], 0, 0, 0);
        }
        __builtin_amdgcn_s_setprio(0);
        SBAR0;

        // ---- phase 2: kk1, n0-1; issue A23(t+1); cvt+write B(t+1); load B(t+2) ----
        #pragma unroll
        for (int m = 0; m < 8; ++m)
            af[m] = *frag128(Ab, wm * 128 + m * 16 + r, 64 + kg * 16);
        #pragma unroll
        for (int n = 0; n < 2; ++n)
            b0[n] = *frag128(Bb, wn * 64 + n * 16 + r, 64 + kg * 16);
        if (hs1) { stageA<LDA>(gAn, nA, 2, tid, wave);
                   stageA<LDA>(gAn, nA, 3, tid, wave); }
        SBAR0;
        if (hs1) {
            asm volatile("s_waitcnt vmcnt(4)" ::: "memory");  // bk(t+1) complete
            SBAR0;
            cvtWriteB(nB, bk, rg, kg8);
            SBAR0;
            if (hs2) { loadB8<LDB>(gBcol, t + 2, bk); SBAR0; }
        }
        asm volatile("s_waitcnt lgkmcnt(0)" ::: "memory");
        SBAR0;
        __builtin_amdgcn_s_setprio(1);
        #pragma unroll
        for (int m = 0; m < 8; ++m) {
            acc[m][0] = MFMA_(af[m], b0[0], acc[m][0], 0, 0, 0);
            acc[m][1] = MFMA_(af[m], b0[1], acc[m][1], 0, 0, 0);
        }
        __builtin_amdgcn_s_setprio(0);
        SBAR0;

        // ---- phase 3: kk1, n2-3 ----
        #pragma unroll
        for (int n = 0; n < 2; ++n)
            bg[n] = *frag128(Bb, wn * 64 + 32 + n * 16 + r, 64 + kg * 16);
        asm volatile("s_waitcnt lgkmcnt(0)" ::: "memory");
        SBAR0;
        __builtin_amdgcn_s_setprio(1);
        #pragma unroll
        for (int m = 0; m < 8; ++m) {
            acc[m][2] = MFMA_(af[m], bg[0], acc[m][2], 0, 0, 0);
            acc[m][3] = MFMA_(af[m], bg[1], acc[m][3], 0, 0, 0);
        }
        __builtin_amdgcn_s_setprio(0);
        SBAR0;

        // ---- boundary: counted wait (B(t+2) stays in flight), barrier ----
        if (hs1) {
            SBAR0;
            if (hs2) asm volatile("s_waitcnt vmcnt(8)" ::: "memory");
            else     asm volatile("s_waitcnt vmcnt(0)" ::: "memory");
            asm volatile("s_waitcnt lgkmcnt(0)" ::: "memory");
            SBAR0;
            __builtin_amdgcn_s_barrier();
            SBAR0;
        }
    }

    // ---------------- epilogue ----------------
    const int row0 = bm * 256 + wm * 128 + kg * 4;   // + m*16 + j
    if constexpr (MODE == 0) {
        // acc[m][n] (n<2) = gate col bn*128+wn*32+n*16+r; acc[m][n+2] = up.
        unsigned short* act = (unsigned short*)Cout + (size_t)e * C_ * I_;
        const int col0 = bn * 128 + wn * 32 + r;
        #pragma unroll
        for (int m = 0; m < 8; ++m)
            #pragma unroll
            for (int n = 0; n < 2; ++n)
                #pragma unroll
                for (int j = 0; j < 4; ++j) {
                    float g = acc[m][n][j], u = acc[m][n + 2][j];
                    float s = g / (1.0f + __expf(-g)) * u;
                    act[(size_t)(row0 + m * 16 + j) * I_ + col0 + n * 16] = f2bf(s);
                }
    } else {
        float* o = (float*)Cout + (size_t)e * C_ * H_;
        const int col0 = bn * 256 + wn * 64 + r;
        #pragma unroll
        for (int m = 0; m < 8; ++m)
            #pragma unroll
            for (int n = 0; n < 4; ++n)
                #pragma unroll
                for (int j = 0; j < 4; ++j)
                    o[(size_t)(row0 + m * 16 + j) * H_ + col0 + n * 16] = acc[m][n][j];
    }
}

// ---------------- launch ----------------
extern "C" void kernel_launch(void* const* d_in, const int* in_sizes, int n_in,
                              void* d_out, int out_size, void* d_ws, size_t ws_size,
                              hipStream_t stream) {
    const float* hs  = (const float*)d_in[0];   // [E][C][H]
    const float* wgu = (const float*)d_in[1];   // [E][H][2I]
    const float* wd  = (const float*)d_in[2];   // [E][I][H]
    float* out = (float*)d_out;

    char* ws = (char*)d_ws;
    unsigned short* Xbf  = (unsigned short*)(ws);                 // 33,554,432 B
    unsigned short* actb = (unsigned short*)(ws + 33554432ull);   // 67,108,864 B

    k_convert<<<2048, 256, 0, stream>>>(hs, Xbf, E_ * C_ * H_ / 8);

    // GEMM1 (fused transpose+silu): X[EC][H] x Wgu native -> act bf16 [EC][I]
    // BM=256 (BMG=4), 128 act cols/block (BNG=32), NT=32 (BK=64). 1024 blocks.
    k_gemm_f<H_ * 2, N1_ * 4, H_ / 64, 4, 32, 0><<<dim3(1024), 512, 0, stream>>>(
        Xbf, wgu, actb, (size_t)C_ * H_, (size_t)H_ * N1_);

    // GEMM2 (fused transpose): act[EC][I] x Wd native -> out f32 [EC][H]
    // BM=256 (BMG=4), BN=256 (BNG=8), NT=64 (BK=64). 256 blocks.
    k_gemm_f<I_ * 2, H_ * 4, I_ / 64, 4, 8, 1><<<dim3(256), 512, 0, stream>>>(
        actb, wd, out, (size_t)C_ * I_, (size_t)I_ * H_);
}